// Round 1
// baseline (78.775 us; speedup 1.0000x reference)
//
#include <hip/hip_runtime.h>

// DirectVG: batched progressive box adjustment.
// boxes [B,N,4] f32, gt [B,M,4] f32 -> all_boxes [B,6,N,4] ++ all_sims [B,6,N,M]
// One wave per (b,n) row; lane l covers gt columns l and l+64.

#define BB 64
#define NN 1000
#define MM 100
#define NITER 5

// exact-order IoU; asm barriers prevent FMA contraction so we match the
// numpy/jax float32 rounding bit-for-bit (argmax ties must not flip).
__device__ __forceinline__ float iou_one(float a0, float a1, float a2, float a3,
                                         const float* __restrict__ g) {
  float g0 = g[0], g1 = g[1], g2 = g[2], g3 = g[3];
  float area_a = (a2 - a0) * (a3 - a1);
  asm volatile("" : "+v"(area_a));
  float area_b = (g2 - g0) * (g3 - g1);
  asm volatile("" : "+v"(area_b));
  float ltx = fmaxf(a0, g0), lty = fmaxf(a1, g1);
  float rbx = fminf(a2, g2), rby = fminf(a3, g3);
  float w = fmaxf(rbx - ltx, 0.0f);
  float h = fmaxf(rby - lty, 0.0f);
  float inter = w * h;
  asm volatile("" : "+v"(inter));
  float uni = (area_a + area_b) - inter;
  return inter / uni;
}

__global__ __launch_bounds__(256) void dvg_kernel(
    const float* __restrict__ boxes, const float* __restrict__ gt,
    float* __restrict__ out) {
  __shared__ float lgt[MM * 5];  // stride-5 pad: 2-way bank alias (free)

  const int tid = threadIdx.x;
  const int wave = tid >> 6;
  const int lane = tid & 63;
  const int blk_per_batch = NN / 4;  // 4 waves/block -> 250 blocks per batch
  const int b = blockIdx.x / blk_per_batch;
  const int n = (blockIdx.x % blk_per_batch) * 4 + wave;

  // stage this batch's gt boxes into LDS (padded)
  for (int i = tid; i < MM * 4; i += 256) {
    lgt[(i >> 2) * 5 + (i & 3)] = gt[b * MM * 4 + i];
  }
  __syncthreads();

  const float4 bx4 = reinterpret_cast<const float4*>(boxes)[b * NN + n];
  float b0 = bx4.x, b1 = bx4.y, b2 = bx4.z, b3 = bx4.w;

  float* __restrict__ outB = out;                            // [B,6,N,4]
  float* __restrict__ outS = out + (size_t)BB * 6 * NN * 4;  // [B,6,N,M]

  const int m1 = lane;
  const int m2 = lane + 64;  // valid iff lane < 36

  for (int it = 0;; ++it) {
    const float iou1 = iou_one(b0, b1, b2, b3, &lgt[m1 * 5]);
    const float iou2 = (m2 < MM) ? iou_one(b0, b1, b2, b3, &lgt[m2 * 5]) : 0.0f;

    const size_t srow = ((size_t)(b * 6 + it) * NN + n) * MM;
    outS[srow + m1] = iou1;                 // 64 lanes contiguous
    if (m2 < MM) outS[srow + m2] = iou2;    // 36 lanes contiguous
    if (lane == 0) {
      reinterpret_cast<float4*>(outB)[(b * 6 + it) * NN + n] =
          make_float4(b0, b1, b2, b3);
    }
    if (it == NITER) break;

    // argmax over M with first-occurrence tie rule (matches jnp.argmax)
    float bv = iou1;
    int bi = m1;
    if (m2 < MM && iou2 > bv) { bv = iou2; bi = m2; }
#pragma unroll
    for (int off = 32; off; off >>= 1) {
      float ov = __shfl_xor(bv, off, 64);
      int oi = __shfl_xor(bi, off, 64);
      if (ov > bv || (ov == bv && oi < bi)) { bv = ov; bi = oi; }
    }

    const float* g = &lgt[bi * 5];
    float g0 = g[0], g1 = g[1], g2 = g[2], g3 = g[3];
    float cx = (b0 + b2) * 0.5f, cy = (b1 + b3) * 0.5f;
    float gcx = (g0 + g2) * 0.5f, gcy = (g1 + g3) * 0.5f;
    float dcx = gcx - cx, dcy = gcy - cy;
    float dsx = (g2 - g0) - (b2 - b0);
    float dsy = (g3 - g1) - (b3 - b1);
    float px = 0.45f * dcx;
    asm volatile("" : "+v"(px));
    float py = 0.45f * dcy;
    asm volatile("" : "+v"(py));
    float qx = 0.4f * (dsx - dcx);
    asm volatile("" : "+v"(qx));
    float qy = 0.4f * (dsy - dcy);
    asm volatile("" : "+v"(qy));
    b0 = b0 + px;
    b1 = b1 + py;
    b2 = (b2 + px) + qx;
    b3 = (b3 + py) + qy;
  }
}

extern "C" void kernel_launch(void* const* d_in, const int* in_sizes, int n_in,
                              void* d_out, int out_size, void* d_ws,
                              size_t ws_size, hipStream_t stream) {
  const float* boxes = (const float*)d_in[0];
  const float* gt = (const float*)d_in[1];
  float* out = (float*)d_out;
  const int blocks = BB * (NN / 4);  // 16000 blocks, 4 waves each
  dvg_kernel<<<blocks, 256, 0, stream>>>(boxes, gt, out);
}

// Round 2
// 56.826 us; speedup vs baseline: 1.3862x; 1.3862x over previous
//
#include <hip/hip_runtime.h>

// DirectVG: batched progressive box adjustment.
// boxes [B,N,4] f32, gt [B,M,4] f32 -> all_boxes [B,6,N,4] ++ all_sims [B,6,N,M]
// One wave per (b,n) row; lane l (l<50) owns gt columns m=2l, 2l+1.

#define BB 64
#define NN 1000
#define MM 100
#define NITER 5

__global__ __launch_bounds__(256) void dvg_kernel(
    const float* __restrict__ boxes, const float* __restrict__ gt,
    float* __restrict__ out) {
  __shared__ float4 lgt[MM];  // uniform-index reads broadcast (no conflict)

  const int tid = threadIdx.x;
  const int wave = tid >> 6;
  const int lane = tid & 63;
  const int b = blockIdx.x / (NN / 4);
  const int n = (blockIdx.x % (NN / 4)) * 4 + wave;

  for (int i = tid; i < MM; i += 256)
    lgt[i] = reinterpret_cast<const float4*>(gt)[b * MM + i];
  __syncthreads();

  // loop-invariant per-lane gt boxes and areas (hoisted out of the iter loop)
  const bool act = lane < (MM / 2);
  const int mA = 2 * lane;
  const float4 gA = lgt[act ? mA : 0];
  const float4 gB = lgt[act ? mA + 1 : 0];
  float areaA = (gA.z - gA.x) * (gA.w - gA.y);
  asm("" : "+v"(areaA));
  float areaB = (gB.z - gB.x) * (gB.w - gB.y);
  asm("" : "+v"(areaB));

  const float4 bx = reinterpret_cast<const float4*>(boxes)[b * NN + n];
  float b0 = bx.x, b1 = bx.y, b2 = bx.z, b3 = bx.w;

  float* __restrict__ outB = out;                                // [B,6,N,4]
  float2* __restrict__ outS =
      reinterpret_cast<float2*>(out + (size_t)BB * 6 * NN * 4);  // [B,6,N,M/2]

  for (int it = 0;; ++it) {
    float area = (b2 - b0) * (b3 - b1);
    asm("" : "+v"(area));

    float wA = fmaxf(fminf(b2, gA.z) - fmaxf(b0, gA.x), 0.0f);
    float hA = fmaxf(fminf(b3, gA.w) - fmaxf(b1, gA.y), 0.0f);
    float iA = wA * hA;
    asm("" : "+v"(iA));
    float uA = (area + areaA) - iA;
    float v1 = iA * __builtin_amdgcn_rcpf(uA);

    float wB = fmaxf(fminf(b2, gB.z) - fmaxf(b0, gB.x), 0.0f);
    float hB = fmaxf(fminf(b3, gB.w) - fmaxf(b1, gB.y), 0.0f);
    float iB = wB * hB;
    asm("" : "+v"(iB));
    float uB = (area + areaB) - iB;
    float v2 = iB * __builtin_amdgcn_rcpf(uB);

    const size_t row = (size_t)(b * 6 + it) * NN + n;
    if (act) outS[row * (MM / 2) + lane] = make_float2(v1, v2);
    if (lane == 0)
      reinterpret_cast<float4*>(outB)[row] = make_float4(b0, b1, b2, b3);
    if (it == NITER) break;

    // argmax over M, first-occurrence tie rule (== jnp.argmax):
    // value-only butterfly max, then ballot + ffs for the smallest index.
    float x1 = act ? v1 : -1.0f;
    float x2 = act ? v2 : -1.0f;
    float lm = fmaxf(x1, x2);
#pragma unroll
    for (int off = 32; off; off >>= 1)
      lm = fmaxf(lm, __shfl_xor(lm, off, 64));
    const unsigned long long k1 = __ballot(x1 == lm);
    const unsigned long long k2 = __ballot(x2 == lm);
    const int c1 = k1 ? ((__ffsll(k1) - 1) << 1) : (1 << 30);
    const int c2 = k2 ? (((__ffsll(k2) - 1) << 1) | 1) : (1 << 30);
    const int bi = c1 < c2 ? c1 : c2;

    const float4 g = lgt[bi];  // uniform -> LDS broadcast
    float cx = (b0 + b2) * 0.5f, cy = (b1 + b3) * 0.5f;
    float gcx = (g.x + g.z) * 0.5f, gcy = (g.y + g.w) * 0.5f;
    float dcx = gcx - cx, dcy = gcy - cy;
    float dsx = (g.z - g.x) - (b2 - b0);
    float dsy = (g.w - g.y) - (b3 - b1);
    float px = 0.45f * dcx;
    asm("" : "+v"(px));
    float py = 0.45f * dcy;
    asm("" : "+v"(py));
    float qx = 0.4f * (dsx - dcx);
    asm("" : "+v"(qx));
    float qy = 0.4f * (dsy - dcy);
    asm("" : "+v"(qy));
    b0 = b0 + px;
    b1 = b1 + py;
    b2 = (b2 + px) + qx;
    b3 = (b3 + py) + qy;
  }
}

extern "C" void kernel_launch(void* const* d_in, const int* in_sizes, int n_in,
                              void* d_out, int out_size, void* d_ws,
                              size_t ws_size, hipStream_t stream) {
  const float* boxes = (const float*)d_in[0];
  const float* gt = (const float*)d_in[1];
  float* out = (float*)d_out;
  const int blocks = BB * (NN / 4);  // 16000 blocks, 4 waves each
  dvg_kernel<<<blocks, 256, 0, stream>>>(boxes, gt, out);
}

// Round 3
// 52.079 us; speedup vs baseline: 1.5126x; 1.0912x over previous
//
#include <hip/hip_runtime.h>

// DirectVG: batched progressive box adjustment.
// boxes [B,N,4] f32, gt [B,M,4] f32 -> all_boxes [B,6,N,4] ++ all_sims [B,6,N,M]
// One wave per TWO rows (ILP); lane l (l<50) owns gt columns m=2l, 2l+1.
// Argmax: DPP max-reduce (no LDS latency) + ballot/ffs first-occurrence index.

#define BB 64
#define NN 1000
#define MM 100
#define NITER 5

// Full-wave f32 max via DPP; idempotent max needs no row/bank masking.
// Result: all lanes get the max (readlane 63 -> SGPR broadcast).
__device__ __forceinline__ float wave_max64(float v) {
#define STEP(ctrl)                                                            \
  {                                                                           \
    int t_ = __builtin_amdgcn_update_dpp(__float_as_int(v), __float_as_int(v),\
                                         (ctrl), 0xf, 0xf, false);            \
    v = fmaxf(v, __int_as_float(t_));                                         \
  }
  STEP(0x111)  // row_shr:1
  STEP(0x112)  // row_shr:2
  STEP(0x114)  // row_shr:4
  STEP(0x118)  // row_shr:8
  STEP(0x142)  // row_bcast:15
  STEP(0x143)  // row_bcast:31
#undef STEP
  return __int_as_float(__builtin_amdgcn_readlane(__float_as_int(v), 63));
}

__device__ __forceinline__ float iou2(float b0, float b1, float b2, float b3,
                                      const float4 g, float area, float areaG) {
  float w = fmaxf(fminf(b2, g.z) - fmaxf(b0, g.x), 0.0f);
  float h = fmaxf(fminf(b3, g.w) - fmaxf(b1, g.y), 0.0f);
  float i = w * h;
  asm("" : "+v"(i));
  float u = (area + areaG) - i;
  return i * __builtin_amdgcn_rcpf(u);
}

__global__ __launch_bounds__(256) void dvg_kernel(
    const float* __restrict__ boxes, const float* __restrict__ gt,
    float* __restrict__ out) {
  __shared__ float4 lgt[MM];

  const int tid = threadIdx.x;
  const int wave = tid >> 6;
  const int lane = tid & 63;
  const int b = blockIdx.x / (NN / 8);
  const int n0 = (blockIdx.x % (NN / 8)) * 8 + wave * 2;  // rows n0, n0+1

  // issue the row loads before staging so they overlap the LDS fill
  const float4 r0 = reinterpret_cast<const float4*>(boxes)[b * NN + n0];
  const float4 r1 = reinterpret_cast<const float4*>(boxes)[b * NN + n0 + 1];

  for (int i = tid; i < MM; i += 256)
    lgt[i] = reinterpret_cast<const float4*>(gt)[b * MM + i];
  __syncthreads();

  // per-lane gt pair (lanes >=50 duplicate m=0,1: harmless for max/ballot)
  const bool act = lane < (MM / 2);
  const int mA = act ? 2 * lane : 0;
  const float4 gA = lgt[mA];
  const float4 gB = lgt[mA + 1];
  float areaA = (gA.z - gA.x) * (gA.w - gA.y);
  asm("" : "+v"(areaA));
  float areaB = (gB.z - gB.x) * (gB.w - gB.y);
  asm("" : "+v"(areaB));

  float a0 = r0.x, a1 = r0.y, a2 = r0.z, a3 = r0.w;  // row 0 box
  float c0 = r1.x, c1 = r1.y, c2 = r1.z, c3 = r1.w;  // row 1 box

  float* __restrict__ outB = out;                                // [B,6,N,4]
  float2* __restrict__ outS =
      reinterpret_cast<float2*>(out + (size_t)BB * 6 * NN * 4);  // [B,6,N,M/2]

  for (int it = 0;; ++it) {
    float ar0 = (a2 - a0) * (a3 - a1);
    asm("" : "+v"(ar0));
    float ar1 = (c2 - c0) * (c3 - c1);
    asm("" : "+v"(ar1));

    const float vA0 = iou2(a0, a1, a2, a3, gA, ar0, areaA);
    const float vB0 = iou2(a0, a1, a2, a3, gB, ar0, areaB);
    const float vA1 = iou2(c0, c1, c2, c3, gA, ar1, areaA);
    const float vB1 = iou2(c0, c1, c2, c3, gB, ar1, areaB);

    const size_t row = (size_t)(b * 6 + it) * NN + n0;
    if (act) {
      outS[row * (MM / 2) + lane] = make_float2(vA0, vB0);
      outS[(row + 1) * (MM / 2) + lane] = make_float2(vA1, vB1);
    }
    if (lane == 0)
      reinterpret_cast<float4*>(outB)[row] = make_float4(a0, a1, a2, a3);
    if (lane == 32)
      reinterpret_cast<float4*>(outB)[row + 1] = make_float4(c0, c1, c2, c3);
    if (it == NITER) break;

    // argmax per row: DPP value max, then ballot+ffs for first occurrence
    const float m0 = wave_max64(fmaxf(vA0, vB0));
    const float m1 = wave_max64(fmaxf(vA1, vB1));
    const unsigned long long kA0 = __ballot(vA0 == m0);
    const unsigned long long kB0 = __ballot(vB0 == m0);
    const unsigned long long kA1 = __ballot(vA1 == m1);
    const unsigned long long kB1 = __ballot(vB1 == m1);
    const int cA0 = kA0 ? ((__ffsll(kA0) - 1) << 1) : (1 << 30);
    const int cB0 = kB0 ? (((__ffsll(kB0) - 1) << 1) | 1) : (1 << 30);
    const int cA1 = kA1 ? ((__ffsll(kA1) - 1) << 1) : (1 << 30);
    const int cB1 = kB1 ? (((__ffsll(kB1) - 1) << 1) | 1) : (1 << 30);
    const int bi0 = cA0 < cB0 ? cA0 : cB0;
    const int bi1 = cA1 < cB1 ? cA1 : cB1;

    const float4 g0 = lgt[bi0];  // uniform -> broadcast
    const float4 g1 = lgt[bi1];

    {
      float dcx = (g0.x + g0.z) * 0.5f - (a0 + a2) * 0.5f;
      float dcy = (g0.y + g0.w) * 0.5f - (a1 + a3) * 0.5f;
      float dsx = (g0.z - g0.x) - (a2 - a0);
      float dsy = (g0.w - g0.y) - (a3 - a1);
      float px = 0.45f * dcx;
      asm("" : "+v"(px));
      float py = 0.45f * dcy;
      asm("" : "+v"(py));
      float qx = 0.4f * (dsx - dcx);
      asm("" : "+v"(qx));
      float qy = 0.4f * (dsy - dcy);
      asm("" : "+v"(qy));
      a0 = a0 + px;
      a1 = a1 + py;
      a2 = (a2 + px) + qx;
      a3 = (a3 + py) + qy;
    }
    {
      float dcx = (g1.x + g1.z) * 0.5f - (c0 + c2) * 0.5f;
      float dcy = (g1.y + g1.w) * 0.5f - (c1 + c3) * 0.5f;
      float dsx = (g1.z - g1.x) - (c2 - c0);
      float dsy = (g1.w - g1.y) - (c3 - c1);
      float px = 0.45f * dcx;
      asm("" : "+v"(px));
      float py = 0.45f * dcy;
      asm("" : "+v"(py));
      float qx = 0.4f * (dsx - dcx);
      asm("" : "+v"(qx));
      float qy = 0.4f * (dsy - dcy);
      asm("" : "+v"(qy));
      c0 = c0 + px;
      c1 = c1 + py;
      c2 = (c2 + px) + qx;
      c3 = (c3 + py) + qy;
    }
  }
}

extern "C" void kernel_launch(void* const* d_in, const int* in_sizes, int n_in,
                              void* d_out, int out_size, void* d_ws,
                              size_t ws_size, hipStream_t stream) {
  const float* boxes = (const float*)d_in[0];
  const float* gt = (const float*)d_in[1];
  float* out = (float*)d_out;
  const int blocks = BB * (NN / 8);  // 8000 blocks, 4 waves x 2 rows each
  dvg_kernel<<<blocks, 256, 0, stream>>>(boxes, gt, out);
}

// Round 4
// 35.901 us; speedup vs baseline: 2.1942x; 1.4506x over previous
//
#include <hip/hip_runtime.h>

// DirectVG: batched progressive box adjustment.
// boxes [B,N,4] f32, gt [B,M,4] f32 -> all_boxes [B,6,N,4] ++ all_sims [B,6,N,M]
//
// Layout: wave = 16 rows x 4 m-groups. lane -> (r = lane&15, g = lane>>4).
// Each lane computes 25 IoUs (m = 25g+j) for row n0+r, argmax tracked in-lane,
// reduced across the 4 g-lanes with 2 shfl_xor steps. Sims transposed through
// a per-wave LDS tile into fully-coalesced dwordx4 stores.

#define BB 64
#define NN 1000
#define MM 100
#define NITER 5
#define RPW 16  // rows per wave
#define MPL 25  // gt boxes per lane
#define SSTR 100  // lsims row stride (floats); (4r+25g+j)%32 -> 2-way = free

__global__ __launch_bounds__(256) void dvg_kernel(
    const float* __restrict__ boxes, const float* __restrict__ gt,
    float* __restrict__ out) {
  __shared__ float4 lgt[MM];              // 1.6 KB
  __shared__ float lsims[4][RPW][SSTR];   // 25.6 KB, per-wave tiles

  const int tid = threadIdx.x;
  const int wv = tid >> 6;
  const int lane = tid & 63;
  const int r = lane & 15;
  const int g = lane >> 4;
  const int b = blockIdx.x >> 4;
  const int n0 = (blockIdx.x & 15) * 64 + wv * RPW;
  const int n = n0 + r;
  const int nc = n < NN ? n : NN - 1;  // clamp tail loads (stores are masked)

  for (int i = tid; i < MM; i += 256)
    lgt[i] = reinterpret_cast<const float4*>(gt)[b * MM + i];
  __syncthreads();

  // loop-invariant gt areas for this lane's 25 columns
  float areaG[MPL];
#pragma unroll
  for (int j = 0; j < MPL; ++j) {
    const float4 q = lgt[g * MPL + j];
    float a = (q.z - q.x) * (q.w - q.y);
    asm("" : "+v"(a));
    areaG[j] = a;
  }

  const float4 bx = reinterpret_cast<const float4*>(boxes)[b * NN + nc];
  float b0 = bx.x, b1 = bx.y, b2 = bx.z, b3 = bx.w;  // replicated across g

  float* __restrict__ outB = out;                       // [B,6,N,4]
  float* __restrict__ outS = out + (size_t)BB * 6 * NN * 4;  // [B,6,N,M]

  // boxes-out transpose: target lane l=4r'+c pulls from src lane 16c+r'
  const int bp_addr = ((((lane & 3) << 4) + (lane >> 2)) << 2);
  const int rr = lane >> 2;          // row for coalesced store phases
  const int q4 = (lane & 3) << 2;    // starting col (floats) within phase

  for (int it = 0;; ++it) {
    float area = (b2 - b0) * (b3 - b1);
    asm("" : "+v"(area));

    // 25 IoUs + in-lane first-occurrence argmax
    float v[MPL];
    float best = -1.0f;
    int bim = 0;
#pragma unroll
    for (int j = 0; j < MPL; ++j) {
      const float4 q = lgt[g * MPL + j];
      const float ltx = fmaxf(b0, q.x), lty = fmaxf(b1, q.y);
      const float rbx = fminf(b2, q.z), rby = fminf(b3, q.w);
      const float w = fmaxf(rbx - ltx, 0.0f);
      const float h = fmaxf(rby - lty, 0.0f);
      float inter = w * h;
      asm("" : "+v"(inter));
      const float uni = (area + areaG[j]) - inter;
      const float val = inter * __builtin_amdgcn_rcpf(uni);
      v[j] = val;
      const bool t = val > best;  // strict > keeps smallest j (first occurrence)
      best = t ? val : best;
      bim = t ? g * MPL + j : bim;
    }

    // stage sims into this wave's LDS tile (2-way bank alias = free)
    {
      float* ls = &lsims[wv][r][g * MPL];
#pragma unroll
      for (int j = 0; j < MPL; ++j) ls[j] = v[j];
    }

    const size_t obase = (size_t)(b * 6 + it) * NN + n0;

    // boxes out: component-select + bpermute -> one dense 256B store
    {
      const float t = g == 0 ? b0 : (g == 1 ? b1 : (g == 2 ? b2 : b3));
      const float bt = __int_as_float(
          __builtin_amdgcn_ds_bpermute(bp_addr, __float_as_int(t)));
      if (n0 + rr < NN) outB[obase * 4 + lane] = bt;
    }

    // sims out: 7 coalesced dwordx4 phases (16 rows x 4 quads each)
    {
      const float* lsr = &lsims[wv][0][0];
      float* os = outS + obase * MM;
      const bool rowok = (n0 + rr) < NN;
#pragma unroll
      for (int i = 0; i < 7; ++i) {
        const int q = i * 4 + (lane & 3);  // quad index 0..27
        if (q < MPL && rowok) {
          const float4 d =
              *reinterpret_cast<const float4*>(&lsr[rr * SSTR + i * 16 + q4]);
          *reinterpret_cast<float4*>(&os[(size_t)rr * MM + i * 16 + q4]) = d;
        }
      }
    }

    if (it == NITER) break;

    // reduce argmax across the 4 g-lanes (prefer larger val, tie -> smaller m)
#pragma unroll
    for (int off = 16; off <= 32; off <<= 1) {
      const float ov = __shfl_xor(best, off, 64);
      const int obi = __shfl_xor(bim, off, 64);
      const bool t = (ov > best) || (ov == best && obi < bim);
      best = t ? ov : best;
      bim = t ? obi : bim;
    }

    const float4 gg = lgt[bim];
    const float dcx = (gg.x + gg.z) * 0.5f - (b0 + b2) * 0.5f;
    const float dcy = (gg.y + gg.w) * 0.5f - (b1 + b3) * 0.5f;
    const float dsx = (gg.z - gg.x) - (b2 - b0);
    const float dsy = (gg.w - gg.y) - (b3 - b1);
    float px = 0.45f * dcx;
    asm("" : "+v"(px));
    float py = 0.45f * dcy;
    asm("" : "+v"(py));
    float qx = 0.4f * (dsx - dcx);
    asm("" : "+v"(qx));
    float qy = 0.4f * (dsy - dcy);
    asm("" : "+v"(qy));
    b0 = b0 + px;
    b1 = b1 + py;
    b2 = (b2 + px) + qx;
    b3 = (b3 + py) + qy;
  }
}

extern "C" void kernel_launch(void* const* d_in, const int* in_sizes, int n_in,
                              void* d_out, int out_size, void* d_ws,
                              size_t ws_size, hipStream_t stream) {
  const float* boxes = (const float*)d_in[0];
  const float* gt = (const float*)d_in[1];
  float* out = (float*)d_out;
  // 16 blocks per batch (16 waves x 16 rows = 1024 >= 1000 rows)
  dvg_kernel<<<BB * 16, 256, 0, stream>>>(boxes, gt, out);
}